// Round 5
// baseline (198.428 us; speedup 1.0000x reference)
//
#include <hip/hip_runtime.h>
#include <math.h>

#define SB 8
#define SS 2048
#define SH 768
#define ALPHA 0.5f

typedef __fp16 f16x8 __attribute__((ext_vector_type(8)));
typedef float f32x4 __attribute__((ext_vector_type(4)));

__device__ __forceinline__ float dot4(float4 a, float4 b) {
  return a.x*b.x + a.y*b.y + a.z*b.z + a.w*b.w;
}
__device__ __forceinline__ unsigned int pk2(float a, float b) {
  return __builtin_bit_cast(unsigned int, __builtin_amdgcn_cvt_pkrtz(a, b));
}

#define GLD(d, p, imm) \
  asm volatile("global_load_dwordx4 %0, %1, off offset:" #imm \
               : "=v"(d) : "v"(p) : "memory")
#define WAITV(n) asm volatile("s_waitcnt vmcnt(" #n ")" ::: "memory")
#define SB0() __builtin_amdgcn_sched_barrier(0)
// 6 B-slice loads: 32 halves (64 B) apart
#define ISSUE_B(B, P) do { \
  GLD(B[0],P,0);   GLD(B[1],P,64);  GLD(B[2],P,128); \
  GLD(B[3],P,192); GLD(B[4],P,256); GLD(B[5],P,320); } while (0)

// ws layout: Khs [SB*SS*SH] f16 (k_hat * km baked)  ~24 MB
//            | ksum [SB*SH] f32 | Nk[8] qsum[8] acc[8] cnt[8]

// K prep: 1024 blocks (XCD-swizzled like band), 16 K-rows/block, 4 rows/wave.
__global__ __launch_bounds__(256) void kprep_kernel(
    const float* __restrict__ K, const float* __restrict__ km,
    const float* __restrict__ qm,
    __fp16* __restrict__ Khs, float* __restrict__ ksum,
    float* __restrict__ Nk, float* __restrict__ qsum) {
  __shared__ float4 red[4][3][64];     // 12 KB
  int blk = blockIdx.x, t = threadIdx.x;
  int w = t >> 6, lane = t & 63;
  int work = (blk & 7) * 128 + (blk >> 3);   // batch -> XCD
  int b = work >> 7;
  int j0 = (work & 127) * 16;
  float4 acc0 = {0,0,0,0}, acc1 = {0,0,0,0}, acc2 = {0,0,0,0};
  for (int jj = 0; jj < 4; ++jj) {
    int j = j0 + 4 * w + jj;
    const float4* rp = (const float4*)(K + ((size_t)b * SS + j) * SH);
    float4 a = rp[lane], b4 = rp[lane + 64], c4 = rp[lane + 128];
    float ssv = dot4(a, a) + dot4(b4, b4) + dot4(c4, c4);
    #pragma unroll
    for (int m = 1; m < 64; m <<= 1) ssv += __shfl_xor(ssv, m, 64);
    float kwj = km[b * SS + j] / fmaxf(sqrtf(ssv), 1e-12f);
    uint2* kr = (uint2*)(Khs + ((size_t)b * SS + j) * SH);
    kr[lane]       = make_uint2(pk2(a.x*kwj,  a.y*kwj),  pk2(a.z*kwj,  a.w*kwj));
    kr[lane + 64]  = make_uint2(pk2(b4.x*kwj, b4.y*kwj), pk2(b4.z*kwj, b4.w*kwj));
    kr[lane + 128] = make_uint2(pk2(c4.x*kwj, c4.y*kwj), pk2(c4.z*kwj, c4.w*kwj));
    acc0.x += a.x*kwj;  acc0.y += a.y*kwj;  acc0.z += a.z*kwj;  acc0.w += a.w*kwj;
    acc1.x += b4.x*kwj; acc1.y += b4.y*kwj; acc1.z += b4.z*kwj; acc1.w += b4.w*kwj;
    acc2.x += c4.x*kwj; acc2.y += c4.y*kwj; acc2.z += c4.z*kwj; acc2.w += c4.w*kwj;
  }
  red[w][0][lane] = acc0; red[w][1][lane] = acc1; red[w][2][lane] = acc2;
  __syncthreads();
  if (t < 192) {
    int s = t >> 6, l = t & 63;
    float4 r0 = red[0][s][l], r1 = red[1][s][l], r2 = red[2][s][l], r3 = red[3][s][l];
    float* kp = ksum + b * SH + (s * 64 + l) * 4;
    atomicAdd(kp + 0, r0.x+r1.x+r2.x+r3.x);
    atomicAdd(kp + 1, r0.y+r1.y+r2.y+r3.y);
    atomicAdd(kp + 2, r0.z+r1.z+r2.z+r3.z);
    atomicAdd(kp + 3, r0.w+r1.w+r2.w+r3.w);
  }
  if (t < 16) {
    float pkm = km[b * SS + j0 + t];
    float pqm = qm[b * SS + j0 + t];
    #pragma unroll
    for (int m = 1; m < 16; m <<= 1) {
      pkm += __shfl_xor(pkm, m, 64);
      pqm += __shfl_xor(pqm, m, 64);
    }
    if (t == 0) { atomicAdd(&Nk[b], pkm); atomicAdd(&qsum[b], pqm); }
  }
}

// Band kernel: 1024 blocks (16 waves/CU), block = 16 q-rows, 4 waves K-split
// (192 each). All prologue loads concurrent (pinned Q), B tiles via pinned
// 2-deep counted-vmcnt pipeline, ONE barrier, all-wave epilogue.
__global__ __launch_bounds__(256, 4) void band_kernel(
    const float* __restrict__ Q, const __fp16* __restrict__ Khs,
    const float* __restrict__ temp, const float* __restrict__ qm,
    const float* __restrict__ ksum, const float* __restrict__ Nkp,
    const float* __restrict__ qsum,
    float* __restrict__ acc, int* __restrict__ cnt, float* __restrict__ out) {
  __shared__ f32x4 sP[4][5][64];       // 20 KB: per-wave S-tile partials
  __shared__ float sSS[4][16], sDD[4][16];
  __shared__ float tab_s[64];
  int tid = threadIdx.x;
  int w = tid >> 6, lane = tid & 63;
  int l15 = lane & 15, quad = lane >> 4;
  int blk = blockIdx.x;
  int work = (blk & 7) * 128 + (blk >> 3);   // batch b -> XCD b
  int b = work >> 7;
  int i0 = (work & 127) * 16;

  if (tid < 64) {
    float invt = 1.0f / temp[0];
    tab_s[tid] = __expf(-ALPHA * fabsf((float)(tid - 31))) * invt;
  }
  float nk = Nkp[b];

  // ---- prologue: pinned Q loads (12) + ksum loads (12), all in flight
  const char* qpB = (const char*)(Q + ((size_t)b * SS + i0 + l15) * SH
                                  + w * 192 + quad * 8);
  const float* ksb = ksum + (size_t)b * SH + w * 192 + quad * 8;
  float4 xq[12];
  GLD(xq[0],qpB,0);    GLD(xq[1],qpB,16);   GLD(xq[2],qpB,128);
  GLD(xq[3],qpB,144);  GLD(xq[4],qpB,256);  GLD(xq[5],qpB,272);
  GLD(xq[6],qpB,384);  GLD(xq[7],qpB,400);  GLD(xq[8],qpB,512);
  GLD(xq[9],qpB,528);  GLD(xq[10],qpB,640); GLD(xq[11],qpB,656);
  float4 ks0[6], ks1[6];
  #pragma unroll
  for (int s = 0; s < 6; ++s) {
    ks0[s] = *(const float4*)(ksb + 32 * s);
    ks1[s] = *(const float4*)(ksb + 32 * s + 4);
  }
  WAITV(0); SB0();
  f16x8 afr[6];
  float ss = 0.f, dd = 0.f;
  #pragma unroll
  for (int s = 0; s < 6; ++s) {
    float4 x0 = xq[2*s], x1 = xq[2*s+1];
    ss += dot4(x0, x0) + dot4(x1, x1);
    dd += dot4(x0, ks0[s]) + dot4(x1, ks1[s]);
    uint4 u = make_uint4(pk2(x0.x, x0.y), pk2(x0.z, x0.w),
                         pk2(x1.x, x1.y), pk2(x1.z, x1.w));
    afr[s] = __builtin_bit_cast(f16x8, u);
  }
  // fold this wave's K-slice over quads; publish per-row partials
  ss += __shfl_xor(ss, 16, 64); ss += __shfl_xor(ss, 32, 64);
  dd += __shfl_xor(dd, 16, 64); dd += __shfl_xor(dd, 32, 64);
  if (quad == 0) { sSS[w][l15] = ss; sDD[w][l15] = dd; }

  // ---- 5 B-tiles, pinned 2-deep counted pipeline (12 outstanding max)
  const __fp16* KbH = Khs + (size_t)b * SS * SH;
  const char* pt[5];
  #pragma unroll
  for (int t = 0; t < 5; ++t) {
    int jc = min(max(i0 - 32 + 16 * t + l15, 0), SS - 1);
    pt[t] = (const char*)(KbH + (size_t)jc * SH + w * 192 + quad * 8);
  }
  f16x8 bqA[6], bqB[6];
  auto dotile = [&](f16x8* bq, int t) {
    f32x4 da = {0,0,0,0}, db = {0,0,0,0};
    da = __builtin_amdgcn_mfma_f32_16x16x32_f16(afr[0], bq[0], da, 0, 0, 0);
    db = __builtin_amdgcn_mfma_f32_16x16x32_f16(afr[1], bq[1], db, 0, 0, 0);
    da = __builtin_amdgcn_mfma_f32_16x16x32_f16(afr[2], bq[2], da, 0, 0, 0);
    db = __builtin_amdgcn_mfma_f32_16x16x32_f16(afr[3], bq[3], db, 0, 0, 0);
    da = __builtin_amdgcn_mfma_f32_16x16x32_f16(afr[4], bq[4], da, 0, 0, 0);
    db = __builtin_amdgcn_mfma_f32_16x16x32_f16(afr[5], bq[5], db, 0, 0, 0);
    sP[w][t][lane] = da + db;
  };
  ISSUE_B(bqA, pt[0]); ISSUE_B(bqB, pt[1]);
  WAITV(6); SB0(); dotile(bqA, 0); ISSUE_B(bqA, pt[2]);
  WAITV(6); SB0(); dotile(bqB, 1); ISSUE_B(bqB, pt[3]);
  WAITV(6); SB0(); dotile(bqA, 2); ISSUE_B(bqA, pt[4]);
  WAITV(6); SB0(); dotile(bqB, 3);
  WAITV(0); SB0(); dotile(bqA, 4);

  __syncthreads();                      // everything drained; one barrier total

  // ---- epilogue (all waves redundantly; wave 0 publishes)
  float qws[4], d0s[4];
  #pragma unroll
  for (int reg = 0; reg < 4; ++reg) {
    int r = quad * 4 + reg;
    float ssr = sSS[0][r] + sSS[1][r] + sSS[2][r] + sSS[3][r];
    float ddr = sDD[0][r] + sDD[1][r] + sDD[2][r] + sDD[3][r];
    qws[reg] = qm[b * SS + i0 + r] / fmaxf(sqrtf(ssr), 1e-12f);
    d0s[reg] = ddr;
  }
  float an[4] = {0,0,0,0}, ad[4] = {0,0,0,0};
  #pragma unroll
  for (int t = 0; t < 5; ++t) {
    f32x4 v = sP[0][t][lane] + sP[1][t][lane] + sP[2][t][lane] + sP[3][t][lane];
    int j = i0 - 32 + 16 * t + l15;
    float vmask = ((unsigned)j < SS) ? 1.0f : 0.0f;
    int idxb = 16 * t + l15 - 1;        // = (j - i0) + 31
    #pragma unroll
    for (int reg = 0; reg < 4; ++reg) {
      float sv = v[reg] * qws[reg];     // kw baked into Khs
      int idx = min(max(idxb - quad * 4 - reg, 0), 63);
      float ev = (__expf(sv * tab_s[idx]) - 1.0f) * vmask;
      an[reg] += ev * sv;
      ad[reg] += ev;
    }
  }
  float tot = 0.f;
  #pragma unroll
  for (int reg = 0; reg < 4; ++reg) {
    float a = an[reg], e = ad[reg];
    a += __shfl_xor(a, 1, 64); a += __shfl_xor(a, 2, 64);
    a += __shfl_xor(a, 4, 64); a += __shfl_xor(a, 8, 64);
    e += __shfl_xor(e, 1, 64); e += __shfl_xor(e, 2, 64);
    e += __shfl_xor(e, 4, 64); e += __shfl_xor(e, 8, 64);
    tot += (qws[reg] * d0s[reg] + a) / (nk + e);
  }
  tot += __shfl_xor(tot, 16, 64);       // sum the 4 quads' row-groups
  tot += __shfl_xor(tot, 32, 64);
  if (tid == 0) {
    atomicAdd(&acc[b], tot);
    __threadfence();
    if (atomicAdd(&cnt[b], 1) == 127) { // last of 128 blocks for batch b
      float a2 = atomicAdd(&acc[b], 0.0f);
      out[b] = a2 / fmaxf(qsum[b], 1.0f);
    }
  }
}

extern "C" void kernel_launch(void* const* d_in, const int* in_sizes, int n_in,
                              void* d_out, int out_size, void* d_ws, size_t ws_size,
                              hipStream_t stream) {
  const float* Q    = (const float*)d_in[0];
  const float* K    = (const float*)d_in[1];
  const float* qm   = (const float*)d_in[2];
  const float* km   = (const float*)d_in[3];
  const float* temp = (const float*)d_in[4];
  float* outp = (float*)d_out;

  const size_t KHS_BYTES = (size_t)SB * SS * SH * 2;  // ~24 MB (fits ws, proven)
  __fp16* Khs = (__fp16*)d_ws;
  float* ksum = (float*)((char*)d_ws + KHS_BYTES);
  float* Nk   = ksum + SB * SH;
  float* qsum = Nk + 8;
  float* accb = qsum + 8;
  int*   cnt  = (int*)(accb + 8);

  (void)hipMemsetAsync(ksum, 0, (SB * SH + 32) * sizeof(float), stream);

  kprep_kernel<<<1024, 256, 0, stream>>>(K, km, qm, Khs, ksum, Nk, qsum);
  band_kernel<<<1024, 256, 0, stream>>>(Q, Khs, temp, qm, ksum, Nk,
                                        qsum, accb, cnt, outp);
}